// Round 12
// baseline (537.040 us; speedup 1.0000x reference)
//
#include <hip/hip_runtime.h>
#include <hip/hip_bf16.h>

#define N_NODES 100000
#define N_EDGES 1600000
#define EQ 400000  // edges per carrier kernel (4 carriers)
#define DIN 165
#define DHID 82
#define DH 128
#define DG 64
#define XPS 168   // padded row stride for Xp and Y (f16) ; 336B rows, 16B aligned
#define HS 88     // padded row stride for H (f16) ; 176B rows, 16B aligned
#define SLOTS 60  // padded adjacency slots per node; P(deg>60) ~ 1e-10
#define SCB 256   // scatter-role blocks per carrier kernel (8 XCD-slice groups of 32)
#define NSL (N_NODES / 8)  // 12500 nodes per XCD slice

typedef _Float16 f16;
typedef f16 f16x8 __attribute__((ext_vector_type(8)));
typedef f16 f16x4 __attribute__((ext_vector_type(4)));
typedef float f32x4 __attribute__((ext_vector_type(4)));

#define MFMA16(a, b, c) __builtin_amdgcn_mfma_f32_16x16x32_f16(a, b, c, 0, 0, 0)

// MFMA 16x16x32 fragment layouts (verified, guide m89/m120):
//   A[m][k]: m = lane&15, k = (lane>>4)*8 + j
//   B[k][n]: n = lane&15, k = (lane>>4)*8 + j
//   D[m][n]: n = lane&15, m = (lane>>4)*4 + reg

// XCD-sliced scatter (round-12): the fused count+scatter atomics to cnt[] were
// hammered from all 8 XCDs -> every line ping-pongs through the device coherence
// point (carriers floored at ~60us regardless of SCB; Occ 17% = scatter tail).
// Slice by dst: group s = blockIdx&7 (XCD id under round-robin dispatch) handles
// only dst in [s*12500, (s+1)*12500) -> each cnt/slots line owned by ONE XCD.
// Each group scans the full edge range (dst re-read x8 = 12.8MB, L3-absorbed).
// Correct for ANY block->XCD mapping; locality is the heuristic part.
__device__ __forceinline__ void scatter_edges(int e0, int e1, int b, int tid,
                                              const int* __restrict__ dst,
                                              const int* __restrict__ src,
                                              int* __restrict__ cnt,
                                              int* __restrict__ slots) {
    int slice = b & 7;
    int lo = slice * NSL, hi = lo + NSL;
    int tg = (b >> 3) * 256 + tid;              // 0..8191 within slice group
#pragma unroll 4
    for (int e = e0 + tg; e < e1; e += (SCB / 8) * 256) {
        int d = dst[e];
        if (d >= lo && d < hi) {
            int r = atomicAdd(&cnt[d], 1);
            if (r < SLOTS) slots[(long)d * SLOTS + r] = src[e];
        }
    }
}

// ============ K1: xpad (BW-bound) + scatter role (edges [0,EQ)) ============
__global__ __launch_bounds__(256) void xpad_kernel(const float* __restrict__ x,
                                                   f16* __restrict__ Xp,
                                                   const int* __restrict__ dst,
                                                   const int* __restrict__ src,
                                                   int* __restrict__ cnt,
                                                   int* __restrict__ slots) {
    if (blockIdx.x < SCB) {
        scatter_edges(0, EQ, blockIdx.x, threadIdx.x, dst, src, cnt, slots);
        return;
    }
    int gid = (blockIdx.x - SCB) * 256 + threadIdx.x;
    if (gid >= N_NODES * 42) return;
    int node = gid / 42, g = gid % 42;
    int col0 = g * 4;
    f16x4 o;
#pragma unroll
    for (int j = 0; j < 4; j++) {
        int c = col0 + j;
        o[j] = (f16)((c < DIN) ? x[(long)node * DIN + c] : 0.f);
    }
    *((f16x4*)(Xp + (long)node * XPS + col0)) = o;
}

// ============ K2: scatter role (edges [EQ,2EQ)) + H = relu(Xp@W1) ============
__global__ __launch_bounds__(256) void h_fill_kernel(const f16* __restrict__ Xp,
                                                     const float* __restrict__ w1,
                                                     f16* __restrict__ H,
                                                     const int* __restrict__ dst,
                                                     const int* __restrict__ src,
                                                     int* __restrict__ cnt,
                                                     int* __restrict__ slots) {
    int tid = threadIdx.x, wave = tid >> 6, lane = tid & 63;
    if (blockIdx.x < SCB) {
        scatter_edges(EQ, 2 * EQ, blockIdx.x, tid, dst, src, cnt, slots);
        return;
    }
    int q = lane >> 4, l16 = lane & 15;
    int blk = blockIdx.x - SCB;                 // 768 GEMM blocks; SCB%8==0 keeps XCD map
    int g = (blk >> 3) & 1;                     // col group
    int chunk = (blk & 7) + 8 * (blk >> 4);     // 0..383
    int nbase = g * 48;
    f16x8 bf[3][6];
#pragma unroll
    for (int nt = 0; nt < 3; nt++) {
        int col = nbase + nt * 16 + l16;
#pragma unroll
        for (int ks = 0; ks < 6; ks++) {
            int kb = ks * 32 + q * 8;
            f16x8 b;
#pragma unroll
            for (int j = 0; j < 8; j++) {
                int k = kb + j;
                b[j] = (f16)((k < DIN && col < DHID) ? w1[k * DHID + col] : 0.f);
            }
            bf[nt][ks] = b;
        }
    }
    for (int mt = chunk * 4 + wave; mt < 6250; mt += 1536) {
        const f16* xr = Xp + (long)(mt * 16 + l16) * XPS;
        f32x4 acc[3];
#pragma unroll
        for (int nt = 0; nt < 3; nt++) acc[nt] = (f32x4){0.f, 0.f, 0.f, 0.f};
#pragma unroll
        for (int ks = 0; ks < 6; ks++) {
            f16x8 a = *((const f16x8*)(xr + ks * 32 + q * 8));
#pragma unroll
            for (int nt = 0; nt < 3; nt++) acc[nt] = MFMA16(a, bf[nt][ks], acc[nt]);
        }
#pragma unroll
        for (int nt = 0; nt < 3; nt++) {
            int col = nbase + nt * 16 + l16;
            if (col < HS) {
#pragma unroll
                for (int r = 0; r < 4; r++) {
                    int node = mt * 16 + q * 4 + r;
                    H[(long)node * HS + col] = (f16)fmaxf(acc[nt][r], 0.f);
                }
            }
        }
    }
}

// ============ K3: scatter role (edges [2EQ,3EQ)) + Y = Xp * sigmoid(2*(H @ W2pad)) ============
__global__ __launch_bounds__(256) void y_kernel(const f16* __restrict__ Xp,
                                                const f16* __restrict__ H,
                                                const float* __restrict__ w2,
                                                f16* __restrict__ Y,
                                                const int* __restrict__ dst,
                                                const int* __restrict__ src,
                                                int* __restrict__ cnt,
                                                int* __restrict__ slots) {
    int tid = threadIdx.x, wave = tid >> 6, lane = tid & 63;
    if (blockIdx.x < SCB) {
        scatter_edges(2 * EQ, 3 * EQ, blockIdx.x, tid, dst, src, cnt, slots);
        return;
    }
    int q = lane >> 4, l16 = lane & 15;
    int blk = blockIdx.x - SCB;                 // 1536 GEMM blocks
    int g = (blk >> 3) & 3;                     // 4 col groups
    int chunk = (blk & 7) + 8 * (blk >> 5);     // 0..383
    int nbase = g * 48;
    f16x8 bf[3][3];
#pragma unroll
    for (int nt = 0; nt < 3; nt++) {
        int col = nbase + nt * 16 + l16;
#pragma unroll
        for (int ks = 0; ks < 3; ks++) {
            int kb = ks * 32 + q * 8;
            f16x8 b;
#pragma unroll
            for (int j = 0; j < 8; j++) {
                int k = kb + j;
                b[j] = (f16)((k < DHID && col < DIN) ? w2[k * DIN + col] : 0.f);
            }
            bf[nt][ks] = b;
        }
    }
    for (int mt = chunk * 4 + wave; mt < 6250; mt += 1536) {
        const f16* hr = H + (long)(mt * 16 + l16) * HS;
        f32x4 acc[3];
#pragma unroll
        for (int nt = 0; nt < 3; nt++) acc[nt] = (f32x4){0.f, 0.f, 0.f, 0.f};
#pragma unroll
        for (int ks = 0; ks < 3; ks++) {
            f16x8 a = *((const f16x8*)(hr + ks * 32 + q * 8));
#pragma unroll
            for (int nt = 0; nt < 3; nt++) acc[nt] = MFMA16(a, bf[nt][ks], acc[nt]);
        }
#pragma unroll
        for (int nt = 0; nt < 3; nt++) {
            int col = nbase + nt * 16 + l16;
            if (col < XPS) {
#pragma unroll
                for (int r = 0; r < 4; r++) {
                    int node = mt * 16 + q * 4 + r;
                    float gg = 1.f / (1.f + __expf(-2.f * acc[nt][r]));
                    float xv = (float)Xp[(long)node * XPS + col];
                    Y[(long)node * XPS + col] = (f16)(xv * gg);
                }
            }
        }
    }
}

// ============ K4: scatter role (edges [3EQ,4EQ)) + t_l = Y@WL ; x2pre = Y@WR + bl ============
__global__ __launch_bounds__(256) void sage_lin_kernel(const f16* __restrict__ Y,
                                                       const float* __restrict__ wl,
                                                       const float* __restrict__ wr,
                                                       const float* __restrict__ bl,
                                                       f16* __restrict__ t_l,
                                                       f16* __restrict__ x2,
                                                       const int* __restrict__ dst,
                                                       const int* __restrict__ src,
                                                       int* __restrict__ cnt,
                                                       int* __restrict__ slots) {
    int tid = threadIdx.x, wave = tid >> 6, lane = tid & 63;
    if (blockIdx.x < SCB) {
        scatter_edges(3 * EQ, N_EDGES, blockIdx.x, tid, dst, src, cnt, slots);
        return;
    }
    int q = lane >> 4, l16 = lane & 15;
    int blk = blockIdx.x - SCB;                 // 1536 GEMM blocks
    int g = (blk >> 3) & 3;                     // 0,1 -> WL ; 2,3 -> WR
    int chunk = (blk & 7) + 8 * (blk >> 5);     // 0..383
    bool isR = (g >= 2);
    const float* W = isR ? wr : wl;
    int cbase = (g & 1) * 64;
    f16x8 bf[4][6];
    float blv[4];
#pragma unroll
    for (int nt = 0; nt < 4; nt++) {
        int col = cbase + nt * 16 + l16;
        blv[nt] = isR ? bl[col] : 0.f;
#pragma unroll
        for (int ks = 0; ks < 6; ks++) {
            int kb = ks * 32 + q * 8;
            f16x8 b;
#pragma unroll
            for (int j = 0; j < 8; j++) {
                int k = kb + j;
                b[j] = (f16)((k < DIN) ? W[k * DH + col] : 0.f);
            }
            bf[nt][ks] = b;
        }
    }
    for (int mt = chunk * 4 + wave; mt < 6250; mt += 1536) {
        const f16* yrow = Y + (long)(mt * 16 + l16) * XPS;
        f32x4 acc[4];
#pragma unroll
        for (int nt = 0; nt < 4; nt++) acc[nt] = (f32x4){0.f, 0.f, 0.f, 0.f};
#pragma unroll
        for (int ks = 0; ks < 6; ks++) {
            f16x8 a = *((const f16x8*)(yrow + ks * 32 + q * 8));
#pragma unroll
            for (int nt = 0; nt < 4; nt++) acc[nt] = MFMA16(a, bf[nt][ks], acc[nt]);
        }
#pragma unroll
        for (int nt = 0; nt < 4; nt++) {
            int col = cbase + nt * 16 + l16;
#pragma unroll
            for (int r = 0; r < 4; r++) {
                int node = mt * 16 + q * 4 + r;
                if (isR)
                    x2[(long)node * DH + col] = (f16)(acc[nt][r] + blv[nt]);
                else
                    t_l[(long)node * DH + col] = (f16)acc[nt][r];
            }
        }
    }
}

// ============ SAGE aggregate: x2 = relu(x2pre + mean(t_l[src])) — padded adjacency ============
// At the random-gather pattern floor (~3.6 TB/s effective; round-11 unroll A/B null).
__global__ __launch_bounds__(256) void sage_agg_kernel(const f16* __restrict__ t_l,
                                                       const int* __restrict__ cnt,
                                                       const int* __restrict__ slots,
                                                       f16* __restrict__ x2) {
    int wid = threadIdx.x >> 6, lane = threadIdx.x & 63;
    int i = blockIdx.x * 4 + wid;
    int deg = min(cnt[i], SLOTS);
    int quarter = lane >> 4, fq = lane & 15;
    // hoisted independent load: its latency hides under the gather
    f16x8 pre = *((const f16x8*)(x2 + (long)i * DH + fq * 8));
    float acc[8];
#pragma unroll
    for (int k = 0; k < 8; k++) acc[k] = 0.f;
    int sn_v = (lane < deg) ? slots[(long)i * SLOTS + lane] : 0;
    int jmax = (deg + 3) >> 2;
#pragma unroll 4
    for (int j = 0; j < jmax; j++) {
        int idx = 4 * j + quarter;
        int sn = __shfl(sn_v, idx);
        float v = (idx < deg) ? 1.f : 0.f;
        f16x8 p = *((const f16x8*)(t_l + ((long)sn << 7) + fq * 8));
#pragma unroll
        for (int k = 0; k < 8; k++) acc[k] = fmaf(v, (float)p[k], acc[k]);
    }
#pragma unroll
    for (int k = 0; k < 8; k++) {
        acc[k] += __shfl_xor(acc[k], 16);
        acc[k] += __shfl_xor(acc[k], 32);
    }
    if (quarter == 0) {
        float inv = 1.f / fmaxf((float)deg, 1.f);
        f16x8 o;
#pragma unroll
        for (int k = 0; k < 8; k++) o[k] = (f16)fmaxf((float)pre[k] + acc[k] * inv, 0.f);
        *((f16x8*)(x2 + (long)i * DH + fq * 8)) = o;
    }
}

// ============ K5: h = x2@gw (f16), a_s/a_d row-dots ============
__global__ __launch_bounds__(256) void gat_h_kernel(const f16* __restrict__ x2,
                                                    const float* __restrict__ gw,
                                                    const float* __restrict__ att_s_w,
                                                    const float* __restrict__ att_d_w,
                                                    f16* __restrict__ h,
                                                    float* __restrict__ a_s,
                                                    float* __restrict__ a_d) {
    int tid = threadIdx.x, wave = tid >> 6, lane = tid & 63;
    int q = lane >> 4, l16 = lane & 15;
    f16x8 bf[4][4];
    float asw[4], adw[4];
#pragma unroll
    for (int nt = 0; nt < 4; nt++) {
        int col = nt * 16 + l16;
        asw[nt] = att_s_w[col];
        adw[nt] = att_d_w[col];
#pragma unroll
        for (int ks = 0; ks < 4; ks++) {
            int kb = ks * 32 + q * 8;
            f16x8 b;
#pragma unroll
            for (int j = 0; j < 8; j++) b[j] = (f16)gw[(kb + j) * DG + col];
            bf[nt][ks] = b;
        }
    }
    int stride = gridDim.x * 4;
    for (int mt = blockIdx.x * 4 + wave; mt < 6250; mt += stride) {
        const f16* xr = x2 + (long)(mt * 16 + l16) * DH;
        f32x4 acc[4];
#pragma unroll
        for (int nt = 0; nt < 4; nt++) acc[nt] = (f32x4){0.f, 0.f, 0.f, 0.f};
#pragma unroll
        for (int ks = 0; ks < 4; ks++) {
            f16x8 a = *((const f16x8*)(xr + ks * 32 + q * 8));
#pragma unroll
            for (int nt = 0; nt < 4; nt++) acc[nt] = MFMA16(a, bf[nt][ks], acc[nt]);
        }
#pragma unroll
        for (int r = 0; r < 4; r++) {
            int node = mt * 16 + q * 4 + r;
            float vs = 0.f, vd = 0.f;
#pragma unroll
            for (int nt = 0; nt < 4; nt++) {
                float hv = acc[nt][r];
                h[(long)node * DG + nt * 16 + l16] = (f16)hv;
                vs += hv * asw[nt];
                vd += hv * adw[nt];
            }
#pragma unroll
            for (int off = 1; off < 16; off <<= 1) {
                vs += __shfl_xor(vs, off);
                vd += __shfl_xor(vd, off);
            }
            if (l16 == 0) {
                a_s[node] = vs;
                a_d[node] = vd;
            }
        }
    }
}

// ============ GAT aggregate + bias + relu + Cheb(64->1) + sigmoid — padded adjacency ============
__device__ __forceinline__ float leaky02(float v) { return v > 0.f ? v : 0.2f * v; }

__global__ __launch_bounds__(256) void gat_agg_kernel(const f16* __restrict__ h,
                                                      const float* __restrict__ a_s,
                                                      const float* __restrict__ a_d,
                                                      const int* __restrict__ cnt,
                                                      const int* __restrict__ slots,
                                                      const float* __restrict__ gat_b,
                                                      const float* __restrict__ cheb_w,
                                                      const float* __restrict__ cheb_b,
                                                      float* __restrict__ out) {
    int wid = threadIdx.x >> 6, lane = threadIdx.x & 63;
    int i = blockIdx.x * 4 + wid;
    int deg = min(cnt[i], SLOTS);
    int quarter = lane >> 4, fq = lane & 15;
    float adi = a_d[i];
    // hoisted epilogue loads: their latency hides under the gather loop
    f16x4 ph = *((const f16x4*)(h + ((long)i << 6) + fq * 4));
    float4 gb = ((const float4*)gat_b)[fq];
    float4 cw = ((const float4*)cheb_w)[fq];
    float wself = __expf(leaky02(a_s[i] + adi));
    float acc[4] = {0.f, 0.f, 0.f, 0.f};
    int sn_v = (lane < deg) ? slots[(long)i * SLOTS + lane] : 0;
    float ev = 0.f;
    if (lane < deg) ev = __expf(leaky02(a_s[sn_v] + adi));
    float sv = ev;
    int jmax = (deg + 3) >> 2;
#pragma unroll 4
    for (int j = 0; j < jmax; j++) {
        int idx = 4 * j + quarter;               // idx>=deg -> ev shfl gives 0
        int sn = __shfl(sn_v, idx);
        float w = __shfl(ev, idx);
        f16x4 p = *((const f16x4*)(h + ((long)sn << 6) + fq * 4));
#pragma unroll
        for (int k = 0; k < 4; k++) acc[k] = fmaf(w, (float)p[k], acc[k]);
    }
#pragma unroll
    for (int off = 32; off > 0; off >>= 1) sv += __shfl_xor(sv, off);
#pragma unroll
    for (int k = 0; k < 4; k++) {
        acc[k] += __shfl_xor(acc[k], 16);
        acc[k] += __shfl_xor(acc[k], 32);
    }
    if (quarter == 0) {
        float s = sv + wself;
        float gbv[4] = {gb.x, gb.y, gb.z, gb.w};
        float cwv[4] = {cw.x, cw.y, cw.z, cw.w};
        float inv = 1.f / s;
        float z = 0.f;
#pragma unroll
        for (int k = 0; k < 4; k++) {
            float o = fmaxf(fmaf(wself, (float)ph[k], acc[k]) * inv + gbv[k], 0.f);
            z = fmaf(o, cwv[k], z);
        }
#pragma unroll
        for (int off = 8; off > 0; off >>= 1) z += __shfl_xor(z, off);
        if (fq == 0) out[i] = 1.f / (1.f + __expf(-(z + cheb_b[0])));
    }
}

extern "C" void kernel_launch(void* const* d_in, const int* in_sizes, int n_in,
                              void* d_out, int out_size, void* d_ws, size_t ws_size,
                              hipStream_t stream) {
    const float* x       = (const float*)d_in[0];
    const int*   eidx    = (const int*)d_in[1];
    const float* fb_w1   = (const float*)d_in[2];
    const float* fb_w2   = (const float*)d_in[3];
    const float* sage_wl = (const float*)d_in[4];
    const float* sage_bl = (const float*)d_in[5];
    const float* sage_wr = (const float*)d_in[6];
    const float* gat_w   = (const float*)d_in[7];
    const float* att_src = (const float*)d_in[8];
    const float* att_dst = (const float*)d_in[9];
    const float* gat_b   = (const float*)d_in[10];
    const float* cheb_w  = (const float*)d_in[11];
    const float* cheb_b  = (const float*)d_in[12];

    const int* src = eidx;
    const int* dst = eidx + N_EDGES;

    // workspace layout, peak 109.2 MB:
    //   Xp    @  0.0M  33.6M  (xpad -> y)
    //   H     @ 33.6M  17.6M  (h_fill -> y)
    //   Y     @ 51.2M  33.6M  (y -> sage_lin)
    //   t_l   @  0.0M  25.6M  (sage_lin -> sage_agg; over dead Xp)
    //   x2    @ 25.6M  25.6M  (sage_lin -> gat_h; over dead Xp/H)
    //   h     @ 51.2M  12.8M  (gat_h -> gat_agg; over dead Y)
    //   a_s/d @ 64.0M   0.8M  (gat_h -> gat_agg; over dead Y)
    //   cnt   @ 84.8M   0.4M  (carriers -> gat_agg)
    //   slots @ 85.2M  24.0M  (carriers -> gat_agg)
    char* base = (char*)d_ws;
    f16* Xp  = (f16*)base;
    f16* H   = (f16*)(base + 33600000);
    f16* Y   = (f16*)(base + 51200000);
    f16* t_l = (f16*)base;
    f16* x2  = (f16*)(base + 25600000);
    f16* h   = (f16*)(base + 51200000);
    float* a_s = (float*)(base + 64000000);
    float* a_d = a_s + N_NODES;
    int* cnt   = (int*)(base + 84800000);
    int* slots = (int*)(base + 85200000);

    // Determinism hardening: cnt must start at 0 every launch.
    hipMemsetAsync(cnt, 0, N_NODES * sizeof(int), stream);

    xpad_kernel<<<SCB + (N_NODES * 42 + 255) / 256, 256, 0, stream>>>(
        x, Xp, dst, src, cnt, slots);
    h_fill_kernel<<<SCB + 768, 256, 0, stream>>>(Xp, fb_w1, H, dst, src, cnt, slots);
    y_kernel<<<SCB + 1536, 256, 0, stream>>>(Xp, H, fb_w2, Y, dst, src, cnt, slots);
    sage_lin_kernel<<<SCB + 1536, 256, 0, stream>>>(Y, sage_wl, sage_wr, sage_bl,
                                                    t_l, x2, dst, src, cnt, slots);
    sage_agg_kernel<<<N_NODES / 4, 256, 0, stream>>>(t_l, cnt, slots, x2);
    gat_h_kernel<<<392, 256, 0, stream>>>(x2, gat_w, att_src, att_dst, h, a_s, a_d);
    gat_agg_kernel<<<N_NODES / 4, 256, 0, stream>>>(h, a_s, a_d, cnt, slots, gat_b,
                                                    cheb_w, cheb_b, (float*)d_out);
}

// Round 13
// 424.252 us; speedup vs baseline: 1.2659x; 1.2659x over previous
//
#include <hip/hip_runtime.h>
#include <hip/hip_bf16.h>

#define N_NODES 100000
#define N_EDGES 1600000
#define EQ 400000  // edges per carrier kernel (4 carriers)
#define DIN 165
#define DHID 82
#define DH 128
#define DG 64
#define XPS 168   // padded row stride for Xp and Y (f16) ; 336B rows, 16B aligned
#define HS 88     // padded row stride for H (f16) ; 176B rows, 16B aligned
#define SLOTS 60  // padded adjacency slots per node; P(deg>60) ~ 1e-10
#define SCB 512   // scatter-role blocks per carrier kernel (TLP for the atomic pipe)

typedef _Float16 f16;
typedef f16 f16x8 __attribute__((ext_vector_type(8)));
typedef f16 f16x4 __attribute__((ext_vector_type(4)));
typedef float f32x4 __attribute__((ext_vector_type(4)));

#define MFMA16(a, b, c) __builtin_amdgcn_mfma_f32_16x16x32_f16(a, b, c, 0, 0, 0)

// MFMA 16x16x32 fragment layouts (verified, guide m89/m120):
//   A[m][k]: m = lane&15, k = (lane>>4)*8 + j
//   B[k][n]: n = lane&15, k = (lane>>4)*8 + j
//   D[m][n]: n = lane&15, m = (lane>>4)*4 + reg

// Role-split scatter (round-11 form — round-12's XCD-slicing REGRESSED 426->537:
// device-scope atomics don't ping-pong lines; the x8 redundant edge scan only
// added issue cost). Iterations are independent -> unroll-4 puts 4 atomics in
// flight per thread; SCB=512 doubles scatter TLP vs round-11.
__device__ __forceinline__ void scatter_edges(int e0, int e1, int tg,
                                              const int* __restrict__ dst,
                                              const int* __restrict__ src,
                                              int* __restrict__ cnt,
                                              int* __restrict__ slots) {
#pragma unroll 4
    for (int e = e0 + tg; e < e1; e += SCB * 256) {
        int d = dst[e];
        int r = atomicAdd(&cnt[d], 1);
        if (r < SLOTS) slots[(long)d * SLOTS + r] = src[e];
    }
}

// ============ K1: xpad (BW-bound) + scatter role (edges [0,EQ)) ============
__global__ __launch_bounds__(256) void xpad_kernel(const float* __restrict__ x,
                                                   f16* __restrict__ Xp,
                                                   const int* __restrict__ dst,
                                                   const int* __restrict__ src,
                                                   int* __restrict__ cnt,
                                                   int* __restrict__ slots) {
    if (blockIdx.x < SCB) {
        scatter_edges(0, EQ, blockIdx.x * 256 + threadIdx.x, dst, src, cnt, slots);
        return;
    }
    int gid = (blockIdx.x - SCB) * 256 + threadIdx.x;
    if (gid >= N_NODES * 42) return;
    int node = gid / 42, g = gid % 42;
    int col0 = g * 4;
    f16x4 o;
#pragma unroll
    for (int j = 0; j < 4; j++) {
        int c = col0 + j;
        o[j] = (f16)((c < DIN) ? x[(long)node * DIN + c] : 0.f);
    }
    *((f16x4*)(Xp + (long)node * XPS + col0)) = o;
}

// ============ K2: scatter role (edges [EQ,2EQ)) + H = relu(Xp@W1) ============
__global__ __launch_bounds__(256) void h_fill_kernel(const f16* __restrict__ Xp,
                                                     const float* __restrict__ w1,
                                                     f16* __restrict__ H,
                                                     const int* __restrict__ dst,
                                                     const int* __restrict__ src,
                                                     int* __restrict__ cnt,
                                                     int* __restrict__ slots) {
    int tid = threadIdx.x, wave = tid >> 6, lane = tid & 63;
    if (blockIdx.x < SCB) {
        scatter_edges(EQ, 2 * EQ, blockIdx.x * 256 + tid, dst, src, cnt, slots);
        return;
    }
    int q = lane >> 4, l16 = lane & 15;
    int blk = blockIdx.x - SCB;                 // 768 GEMM blocks; SCB%8==0 keeps XCD map
    int g = (blk >> 3) & 1;                     // col group
    int chunk = (blk & 7) + 8 * (blk >> 4);     // 0..383
    int nbase = g * 48;
    f16x8 bf[3][6];
#pragma unroll
    for (int nt = 0; nt < 3; nt++) {
        int col = nbase + nt * 16 + l16;
#pragma unroll
        for (int ks = 0; ks < 6; ks++) {
            int kb = ks * 32 + q * 8;
            f16x8 b;
#pragma unroll
            for (int j = 0; j < 8; j++) {
                int k = kb + j;
                b[j] = (f16)((k < DIN && col < DHID) ? w1[k * DHID + col] : 0.f);
            }
            bf[nt][ks] = b;
        }
    }
    for (int mt = chunk * 4 + wave; mt < 6250; mt += 1536) {
        const f16* xr = Xp + (long)(mt * 16 + l16) * XPS;
        f32x4 acc[3];
#pragma unroll
        for (int nt = 0; nt < 3; nt++) acc[nt] = (f32x4){0.f, 0.f, 0.f, 0.f};
#pragma unroll
        for (int ks = 0; ks < 6; ks++) {
            f16x8 a = *((const f16x8*)(xr + ks * 32 + q * 8));
#pragma unroll
            for (int nt = 0; nt < 3; nt++) acc[nt] = MFMA16(a, bf[nt][ks], acc[nt]);
        }
#pragma unroll
        for (int nt = 0; nt < 3; nt++) {
            int col = nbase + nt * 16 + l16;
            if (col < HS) {
#pragma unroll
                for (int r = 0; r < 4; r++) {
                    int node = mt * 16 + q * 4 + r;
                    H[(long)node * HS + col] = (f16)fmaxf(acc[nt][r], 0.f);
                }
            }
        }
    }
}

// ============ K3: scatter role (edges [2EQ,3EQ)) + Y = Xp * sigmoid(2*(H @ W2pad)) ============
__global__ __launch_bounds__(256) void y_kernel(const f16* __restrict__ Xp,
                                                const f16* __restrict__ H,
                                                const float* __restrict__ w2,
                                                f16* __restrict__ Y,
                                                const int* __restrict__ dst,
                                                const int* __restrict__ src,
                                                int* __restrict__ cnt,
                                                int* __restrict__ slots) {
    int tid = threadIdx.x, wave = tid >> 6, lane = tid & 63;
    if (blockIdx.x < SCB) {
        scatter_edges(2 * EQ, 3 * EQ, blockIdx.x * 256 + tid, dst, src, cnt, slots);
        return;
    }
    int q = lane >> 4, l16 = lane & 15;
    int blk = blockIdx.x - SCB;                 // 1536 GEMM blocks
    int g = (blk >> 3) & 3;                     // 4 col groups
    int chunk = (blk & 7) + 8 * (blk >> 5);     // 0..383
    int nbase = g * 48;
    f16x8 bf[3][3];
#pragma unroll
    for (int nt = 0; nt < 3; nt++) {
        int col = nbase + nt * 16 + l16;
#pragma unroll
        for (int ks = 0; ks < 3; ks++) {
            int kb = ks * 32 + q * 8;
            f16x8 b;
#pragma unroll
            for (int j = 0; j < 8; j++) {
                int k = kb + j;
                b[j] = (f16)((k < DHID && col < DIN) ? w2[k * DIN + col] : 0.f);
            }
            bf[nt][ks] = b;
        }
    }
    for (int mt = chunk * 4 + wave; mt < 6250; mt += 1536) {
        const f16* hr = H + (long)(mt * 16 + l16) * HS;
        f32x4 acc[3];
#pragma unroll
        for (int nt = 0; nt < 3; nt++) acc[nt] = (f32x4){0.f, 0.f, 0.f, 0.f};
#pragma unroll
        for (int ks = 0; ks < 3; ks++) {
            f16x8 a = *((const f16x8*)(hr + ks * 32 + q * 8));
#pragma unroll
            for (int nt = 0; nt < 3; nt++) acc[nt] = MFMA16(a, bf[nt][ks], acc[nt]);
        }
#pragma unroll
        for (int nt = 0; nt < 3; nt++) {
            int col = nbase + nt * 16 + l16;
            if (col < XPS) {
#pragma unroll
                for (int r = 0; r < 4; r++) {
                    int node = mt * 16 + q * 4 + r;
                    float gg = 1.f / (1.f + __expf(-2.f * acc[nt][r]));
                    float xv = (float)Xp[(long)node * XPS + col];
                    Y[(long)node * XPS + col] = (f16)(xv * gg);
                }
            }
        }
    }
}

// ============ K4: scatter role (edges [3EQ,4EQ)) + t_l = Y@WL ; x2pre = Y@WR + bl ============
__global__ __launch_bounds__(256) void sage_lin_kernel(const f16* __restrict__ Y,
                                                       const float* __restrict__ wl,
                                                       const float* __restrict__ wr,
                                                       const float* __restrict__ bl,
                                                       f16* __restrict__ t_l,
                                                       f16* __restrict__ x2,
                                                       const int* __restrict__ dst,
                                                       const int* __restrict__ src,
                                                       int* __restrict__ cnt,
                                                       int* __restrict__ slots) {
    int tid = threadIdx.x, wave = tid >> 6, lane = tid & 63;
    if (blockIdx.x < SCB) {
        scatter_edges(3 * EQ, N_EDGES, blockIdx.x * 256 + tid, dst, src, cnt, slots);
        return;
    }
    int q = lane >> 4, l16 = lane & 15;
    int blk = blockIdx.x - SCB;                 // 1536 GEMM blocks
    int g = (blk >> 3) & 3;                     // 0,1 -> WL ; 2,3 -> WR
    int chunk = (blk & 7) + 8 * (blk >> 5);     // 0..383
    bool isR = (g >= 2);
    const float* W = isR ? wr : wl;
    int cbase = (g & 1) * 64;
    f16x8 bf[4][6];
    float blv[4];
#pragma unroll
    for (int nt = 0; nt < 4; nt++) {
        int col = cbase + nt * 16 + l16;
        blv[nt] = isR ? bl[col] : 0.f;
#pragma unroll
        for (int ks = 0; ks < 6; ks++) {
            int kb = ks * 32 + q * 8;
            f16x8 b;
#pragma unroll
            for (int j = 0; j < 8; j++) {
                int k = kb + j;
                b[j] = (f16)((k < DIN) ? W[k * DH + col] : 0.f);
            }
            bf[nt][ks] = b;
        }
    }
    for (int mt = chunk * 4 + wave; mt < 6250; mt += 1536) {
        const f16* yrow = Y + (long)(mt * 16 + l16) * XPS;
        f32x4 acc[4];
#pragma unroll
        for (int nt = 0; nt < 4; nt++) acc[nt] = (f32x4){0.f, 0.f, 0.f, 0.f};
#pragma unroll
        for (int ks = 0; ks < 6; ks++) {
            f16x8 a = *((const f16x8*)(yrow + ks * 32 + q * 8));
#pragma unroll
            for (int nt = 0; nt < 4; nt++) acc[nt] = MFMA16(a, bf[nt][ks], acc[nt]);
        }
#pragma unroll
        for (int nt = 0; nt < 4; nt++) {
            int col = cbase + nt * 16 + l16;
#pragma unroll
            for (int r = 0; r < 4; r++) {
                int node = mt * 16 + q * 4 + r;
                if (isR)
                    x2[(long)node * DH + col] = (f16)(acc[nt][r] + blv[nt]);
                else
                    t_l[(long)node * DH + col] = (f16)acc[nt][r];
            }
        }
    }
}

// ============ SAGE aggregate: x2 = relu(x2pre + mean(t_l[src])) — padded adjacency ============
// At the random-gather pattern floor (~3.6 TB/s effective; round-11 unroll A/B null).
__global__ __launch_bounds__(256) void sage_agg_kernel(const f16* __restrict__ t_l,
                                                       const int* __restrict__ cnt,
                                                       const int* __restrict__ slots,
                                                       f16* __restrict__ x2) {
    int wid = threadIdx.x >> 6, lane = threadIdx.x & 63;
    int i = blockIdx.x * 4 + wid;
    int deg = min(cnt[i], SLOTS);
    int quarter = lane >> 4, fq = lane & 15;
    // hoisted independent load: its latency hides under the gather
    f16x8 pre = *((const f16x8*)(x2 + (long)i * DH + fq * 8));
    float acc[8];
#pragma unroll
    for (int k = 0; k < 8; k++) acc[k] = 0.f;
    int sn_v = (lane < deg) ? slots[(long)i * SLOTS + lane] : 0;
    int jmax = (deg + 3) >> 2;
#pragma unroll 4
    for (int j = 0; j < jmax; j++) {
        int idx = 4 * j + quarter;
        int sn = __shfl(sn_v, idx);
        float v = (idx < deg) ? 1.f : 0.f;
        f16x8 p = *((const f16x8*)(t_l + ((long)sn << 7) + fq * 8));
#pragma unroll
        for (int k = 0; k < 8; k++) acc[k] = fmaf(v, (float)p[k], acc[k]);
    }
#pragma unroll
    for (int k = 0; k < 8; k++) {
        acc[k] += __shfl_xor(acc[k], 16);
        acc[k] += __shfl_xor(acc[k], 32);
    }
    if (quarter == 0) {
        float inv = 1.f / fmaxf((float)deg, 1.f);
        f16x8 o;
#pragma unroll
        for (int k = 0; k < 8; k++) o[k] = (f16)fmaxf((float)pre[k] + acc[k] * inv, 0.f);
        *((f16x8*)(x2 + (long)i * DH + fq * 8)) = o;
    }
}

// ============ K5: h = x2@gw (f16), a_s/a_d row-dots ============
__global__ __launch_bounds__(256) void gat_h_kernel(const f16* __restrict__ x2,
                                                    const float* __restrict__ gw,
                                                    const float* __restrict__ att_s_w,
                                                    const float* __restrict__ att_d_w,
                                                    f16* __restrict__ h,
                                                    float* __restrict__ a_s,
                                                    float* __restrict__ a_d) {
    int tid = threadIdx.x, wave = tid >> 6, lane = tid & 63;
    int q = lane >> 4, l16 = lane & 15;
    f16x8 bf[4][4];
    float asw[4], adw[4];
#pragma unroll
    for (int nt = 0; nt < 4; nt++) {
        int col = nt * 16 + l16;
        asw[nt] = att_s_w[col];
        adw[nt] = att_d_w[col];
#pragma unroll
        for (int ks = 0; ks < 4; ks++) {
            int kb = ks * 32 + q * 8;
            f16x8 b;
#pragma unroll
            for (int j = 0; j < 8; j++) b[j] = (f16)gw[(kb + j) * DG + col];
            bf[nt][ks] = b;
        }
    }
    int stride = gridDim.x * 4;
    for (int mt = blockIdx.x * 4 + wave; mt < 6250; mt += stride) {
        const f16* xr = x2 + (long)(mt * 16 + l16) * DH;
        f32x4 acc[4];
#pragma unroll
        for (int nt = 0; nt < 4; nt++) acc[nt] = (f32x4){0.f, 0.f, 0.f, 0.f};
#pragma unroll
        for (int ks = 0; ks < 4; ks++) {
            f16x8 a = *((const f16x8*)(xr + ks * 32 + q * 8));
#pragma unroll
            for (int nt = 0; nt < 4; nt++) acc[nt] = MFMA16(a, bf[nt][ks], acc[nt]);
        }
#pragma unroll
        for (int r = 0; r < 4; r++) {
            int node = mt * 16 + q * 4 + r;
            float vs = 0.f, vd = 0.f;
#pragma unroll
            for (int nt = 0; nt < 4; nt++) {
                float hv = acc[nt][r];
                h[(long)node * DG + nt * 16 + l16] = (f16)hv;
                vs += hv * asw[nt];
                vd += hv * adw[nt];
            }
#pragma unroll
            for (int off = 1; off < 16; off <<= 1) {
                vs += __shfl_xor(vs, off);
                vd += __shfl_xor(vd, off);
            }
            if (l16 == 0) {
                a_s[node] = vs;
                a_d[node] = vd;
            }
        }
    }
}

// ============ GAT aggregate + bias + relu + Cheb(64->1) + sigmoid — padded adjacency ============
__device__ __forceinline__ float leaky02(float v) { return v > 0.f ? v : 0.2f * v; }

__global__ __launch_bounds__(256) void gat_agg_kernel(const f16* __restrict__ h,
                                                      const float* __restrict__ a_s,
                                                      const float* __restrict__ a_d,
                                                      const int* __restrict__ cnt,
                                                      const int* __restrict__ slots,
                                                      const float* __restrict__ gat_b,
                                                      const float* __restrict__ cheb_w,
                                                      const float* __restrict__ cheb_b,
                                                      float* __restrict__ out) {
    int wid = threadIdx.x >> 6, lane = threadIdx.x & 63;
    int i = blockIdx.x * 4 + wid;
    int deg = min(cnt[i], SLOTS);
    int quarter = lane >> 4, fq = lane & 15;
    float adi = a_d[i];
    // hoisted epilogue loads: their latency hides under the gather loop
    f16x4 ph = *((const f16x4*)(h + ((long)i << 6) + fq * 4));
    float4 gb = ((const float4*)gat_b)[fq];
    float4 cw = ((const float4*)cheb_w)[fq];
    float wself = __expf(leaky02(a_s[i] + adi));
    float acc[4] = {0.f, 0.f, 0.f, 0.f};
    int sn_v = (lane < deg) ? slots[(long)i * SLOTS + lane] : 0;
    float ev = 0.f;
    if (lane < deg) ev = __expf(leaky02(a_s[sn_v] + adi));
    float sv = ev;
    int jmax = (deg + 3) >> 2;
#pragma unroll 4
    for (int j = 0; j < jmax; j++) {
        int idx = 4 * j + quarter;               // idx>=deg -> ev shfl gives 0
        int sn = __shfl(sn_v, idx);
        float w = __shfl(ev, idx);
        f16x4 p = *((const f16x4*)(h + ((long)sn << 6) + fq * 4));
#pragma unroll
        for (int k = 0; k < 4; k++) acc[k] = fmaf(w, (float)p[k], acc[k]);
    }
#pragma unroll
    for (int off = 32; off > 0; off >>= 1) sv += __shfl_xor(sv, off);
#pragma unroll
    for (int k = 0; k < 4; k++) {
        acc[k] += __shfl_xor(acc[k], 16);
        acc[k] += __shfl_xor(acc[k], 32);
    }
    if (quarter == 0) {
        float s = sv + wself;
        float gbv[4] = {gb.x, gb.y, gb.z, gb.w};
        float cwv[4] = {cw.x, cw.y, cw.z, cw.w};
        float inv = 1.f / s;
        float z = 0.f;
#pragma unroll
        for (int k = 0; k < 4; k++) {
            float o = fmaxf(fmaf(wself, (float)ph[k], acc[k]) * inv + gbv[k], 0.f);
            z = fmaf(o, cwv[k], z);
        }
#pragma unroll
        for (int off = 8; off > 0; off >>= 1) z += __shfl_xor(z, off);
        if (fq == 0) out[i] = 1.f / (1.f + __expf(-(z + cheb_b[0])));
    }
}

extern "C" void kernel_launch(void* const* d_in, const int* in_sizes, int n_in,
                              void* d_out, int out_size, void* d_ws, size_t ws_size,
                              hipStream_t stream) {
    const float* x       = (const float*)d_in[0];
    const int*   eidx    = (const int*)d_in[1];
    const float* fb_w1   = (const float*)d_in[2];
    const float* fb_w2   = (const float*)d_in[3];
    const float* sage_wl = (const float*)d_in[4];
    const float* sage_bl = (const float*)d_in[5];
    const float* sage_wr = (const float*)d_in[6];
    const float* gat_w   = (const float*)d_in[7];
    const float* att_src = (const float*)d_in[8];
    const float* att_dst = (const float*)d_in[9];
    const float* gat_b   = (const float*)d_in[10];
    const float* cheb_w  = (const float*)d_in[11];
    const float* cheb_b  = (const float*)d_in[12];

    const int* src = eidx;
    const int* dst = eidx + N_EDGES;

    // workspace layout, peak 109.2 MB:
    //   Xp    @  0.0M  33.6M  (xpad -> y)
    //   H     @ 33.6M  17.6M  (h_fill -> y)
    //   Y     @ 51.2M  33.6M  (y -> sage_lin)
    //   t_l   @  0.0M  25.6M  (sage_lin -> sage_agg; over dead Xp)
    //   x2    @ 25.6M  25.6M  (sage_lin -> gat_h; over dead Xp/H)
    //   h     @ 51.2M  12.8M  (gat_h -> gat_agg; over dead Y)
    //   a_s/d @ 64.0M   0.8M  (gat_h -> gat_agg; over dead Y)
    //   cnt   @ 84.8M   0.4M  (carriers -> gat_agg)
    //   slots @ 85.2M  24.0M  (carriers -> gat_agg)
    char* base = (char*)d_ws;
    f16* Xp  = (f16*)base;
    f16* H   = (f16*)(base + 33600000);
    f16* Y   = (f16*)(base + 51200000);
    f16* t_l = (f16*)base;
    f16* x2  = (f16*)(base + 25600000);
    f16* h   = (f16*)(base + 51200000);
    float* a_s = (float*)(base + 64000000);
    float* a_d = a_s + N_NODES;
    int* cnt   = (int*)(base + 84800000);
    int* slots = (int*)(base + 85200000);

    // Determinism hardening: cnt must start at 0 every launch.
    hipMemsetAsync(cnt, 0, N_NODES * sizeof(int), stream);

    xpad_kernel<<<SCB + (N_NODES * 42 + 255) / 256, 256, 0, stream>>>(
        x, Xp, dst, src, cnt, slots);
    h_fill_kernel<<<SCB + 768, 256, 0, stream>>>(Xp, fb_w1, H, dst, src, cnt, slots);
    y_kernel<<<SCB + 1536, 256, 0, stream>>>(Xp, H, fb_w2, Y, dst, src, cnt, slots);
    sage_lin_kernel<<<SCB + 1536, 256, 0, stream>>>(Y, sage_wl, sage_wr, sage_bl,
                                                    t_l, x2, dst, src, cnt, slots);
    sage_agg_kernel<<<N_NODES / 4, 256, 0, stream>>>(t_l, cnt, slots, x2);
    gat_h_kernel<<<392, 256, 0, stream>>>(x2, gat_w, att_src, att_dst, h, a_s, a_d);
    gat_agg_kernel<<<N_NODES / 4, 256, 0, stream>>>(h, a_s, a_d, cnt, slots, gat_b,
                                                    cheb_w, cheb_b, (float*)d_out);
}